// Round 25
// baseline (132.871 us; speedup 1.0000x reference)
//
#include <hip/hip_runtime.h>
#include <math.h>

// SAE hierarchical, R25 = R24 + waves_per_eu(4, 8) -- the last untested
// attribute cell. R24 was time-null but WRITE_SIZE 12->34.5MB revealed
// IN-LOOP spill: body needs ~45 regs, allocator grants 32. Evidence across
// R16-R19: granted VGPR tracks the MIN waves setting (min8->32, min6->40);
// extrapolation min4 -> ~56-64 regs (body fits) while max8 keeps 8-wave/EU
// residency (64 regs still permits 8 waves/EU in HW). Only config that can
// give spill-free inner loop AND full residency. Everything else byte-
// identical to R24 (packed frags, LDS biases, index-only push, 2.1-sigma,
// bit-exact rescue/select/decode).

#define D64   64
#define ROWS  16
#define CAP   128
#define FTILE 256
#define HID1  4096
#define HID2  2048
#define K1    32
#define K2    16

typedef __attribute__((ext_vector_type(8))) short bf16x8;
typedef __attribute__((ext_vector_type(4))) float f32x4;
typedef unsigned long long u64;

__device__ __forceinline__ unsigned short f2bf(float f) {
    unsigned u = __float_as_uint(f);
    return (unsigned short)((u + 0x7FFFu + ((u >> 16) & 1u)) >> 16);
}

__device__ __forceinline__ float wave_sum_f32(float v) {
#pragma unroll
    for (int off = 32; off > 0; off >>= 1) v += __shfl_xor(v, off, 64);
    return v;
}

// prep: W1|W2 fp32 -> bf16, FRAGMENT-PACKED layout (R16/R20 mapping).
__global__ __launch_bounds__(256) void prep_w(const float* __restrict__ W1,
                                              const float* __restrict__ W2,
                                              unsigned short* __restrict__ wh) {
    const int t = blockIdx.x * 256 + threadIdx.x;    // 49152 threads, 8 floats each
    const int fg = t >> 3;                           // global feature 0..6143
    const int k8 = t & 7;                            // 8-halfword chunk
    const int lvl = (fg >= HID1);
    const int f = lvl ? fg - HID1 : fg;
    const float* src = lvl ? (W2 + (size_t)f * D64) : (W1 + (size_t)f * D64);
    const int p = f >> 8, rem = f & 255;
    const int wu = rem >> 5, half = (rem >> 4) & 1, l15 = rem & 15;
    const int frag = half * 2 + (k8 >= 4 ? 1 : 0);
    const int g = k8 & 3;
    float4 a = ((const float4*)src)[k8 * 2];
    float4 b = ((const float4*)src)[k8 * 2 + 1];
    u64 pk0 = (u64)f2bf(a.x) | ((u64)f2bf(a.y) << 16)
            | ((u64)f2bf(a.z) << 32) | ((u64)f2bf(a.w) << 48);
    u64 pk1 = (u64)f2bf(b.x) | ((u64)f2bf(b.y) << 16)
            | ((u64)f2bf(b.z) << 32) | ((u64)f2bf(b.w) << 48);
    const size_t dst = (size_t)(lvl ? HID1 * D64 : 0)
                     + (size_t)(((p * 8 + wu) * 4 + frag) * 512 + (g * 16 + l15) * 8);
    *(u64*)&wh[dst]     = pk0;
    *(u64*)&wh[dst + 4] = pk1;
}

__global__ __launch_bounds__(512)
__attribute__((amdgpu_waves_per_eu(4, 8)))
void sae_hier_mfma(
    const float* __restrict__ x,
    const float* __restrict__ W1,  const float* __restrict__ b1,
    const float* __restrict__ Wd1, const float* __restrict__ bd1,
    const float* __restrict__ W2,  const float* __restrict__ b2,
    const float* __restrict__ Wd2, const float* __restrict__ bd2,
    const unsigned short* __restrict__ wh,
    float* __restrict__ out)
{
    __shared__ uint2 s_buf[ROWS * CAP];                       // 16 KB candidates
    __shared__ __align__(16) float s_xf32[ROWS * D64];        // 4 KB exact input
    __shared__ __align__(16) unsigned short s_ah[ROWS * D64]; // 2 KB bf16 A (linear)
    __shared__ __align__(16) float s_bias[HID1];              // 16 KB staged biases
    __shared__ float s_sig[ROWS];
    __shared__ float s_thr[ROWS];
    __shared__ float s_scale[ROWS];
    __shared__ int   s_cnt[ROWS];
    __shared__ int   s_act[ROWS];
    __shared__ int   s_anybad;

    const int tid  = threadIdx.x;
    const int lane = tid & 63;
    const int wu   = __builtin_amdgcn_readfirstlane(tid >> 6);  // 8 waves
    const int rowbase = blockIdx.x * ROWS;
    const int g   = lane >> 4;
    const int l15 = lane & 15;

    if (tid < ROWS) { s_cnt[tid] = 0; s_scale[tid] = 1.0f; s_act[tid] = 1; }

    // ---- stage (x - b_dec): fp32 exact + bf16 linear + threshold base ----
    if (tid < 256) {
        const int r = tid >> 4, q = tid & 15;                 // 16 rows x 16 quads
        float4 a = ((const float4*)x)[(size_t)(rowbase + r) * 16 + q];
        float4 b = ((const float4*)bd1)[q];
        float4 v = make_float4(a.x - b.x, a.y - b.y, a.z - b.z, a.w - b.w);
        ((float4*)s_xf32)[r * 16 + q] = v;
        u64 pk = (u64)f2bf(v.x) | ((u64)f2bf(v.y) << 16)
               | ((u64)f2bf(v.z) << 32) | ((u64)f2bf(v.w) << 48);
        *(u64*)&s_ah[(r * 16 + q) * 4] = pk;
        float ss = fmaf(v.x, v.x, fmaf(v.y, v.y, fmaf(v.z, v.z, v.w * v.w)));
        ss += __shfl_xor(ss, 1, 64); ss += __shfl_xor(ss, 2, 64);
        ss += __shfl_xor(ss, 4, 64); ss += __shfl_xor(ss, 8, 64);
        if (q == 0) s_sig[r] = 0.2625f * sqrtf(ss);           // 2.1*sigma
    }

// index-only push: rescue overwrites .x with the exact value, so only .y matters.
#define PUSHI(ACC, COLG, U0, U1, U2, U3) { \
    if (ACC[0] > U0) { int s = atomicAdd(&s_cnt[g*4+0], 1); if (s < CAP) s_buf[(g*4+0)*CAP+s].y = (unsigned)(COLG); } \
    if (ACC[1] > U1) { int s = atomicAdd(&s_cnt[g*4+1], 1); if (s < CAP) s_buf[(g*4+1)*CAP+s].y = (unsigned)(COLG); } \
    if (ACC[2] > U2) { int s = atomicAdd(&s_cnt[g*4+2], 1); if (s < CAP) s_buf[(g*4+2)*CAP+s].y = (unsigned)(COLG); } \
    if (ACC[3] > U3) { int s = atomicAdd(&s_cnt[g*4+3], 1); if (s < CAP) s_buf[(g*4+3)*CAP+s].y = (unsigned)(COLG); } }

#pragma unroll 1
    for (int level = 0; level < 2; ++level) {
        const float* We  = level ? W2  : W1;
        const float* be  = level ? b2  : b1;
        const float* Wd  = level ? Wd2 : Wd1;
        const float* bdv = level ? bd2 : bd1;
        const unsigned short* whL = wh + (level ? (size_t)HID1 * D64 : 0);
        const int KSEL   = level ? K2 : K1;
        const int NPASS  = (level ? HID2 : HID1) / FTILE;
        const int NB     = level ? HID2 : HID1;

        // stage biases into LDS (once per level; coalesced float4)
        for (int i = tid; i < NB / 4; i += 512)
            ((float4*)s_bias)[i] = ((const float4*)be)[i];
        __syncthreads();

        // ======== approx GEMM (packed frags, LDS biases, index-only push) ========
#pragma unroll 1
        for (int attempt = 0; attempt < 8; ++attempt) {
            if (tid < ROWS) s_thr[tid] = s_act[tid] ? s_sig[tid] * s_scale[tid] : 3.4e38f;
            __syncthreads();
            bf16x8 a0 = *(const bf16x8*)&s_ah[l15 * D64 + 8 * g];
            bf16x8 a1 = *(const bf16x8*)&s_ah[l15 * D64 + 32 + 8 * g];
            const float t0 = s_thr[g * 4 + 0], t1 = s_thr[g * 4 + 1];
            const float t2 = s_thr[g * 4 + 2], t3 = s_thr[g * 4 + 3];

#pragma unroll 1
            for (int p = 0; p < NPASS; ++p) {
                const unsigned short* wb = whL + (size_t)(p * 8 + wu) * 2048;
                const int fbase = p * FTILE + wu * 32 + l15;
                // batch: 4 packed fragment loads (VMEM) + 2 bias ds_reads
                bf16x8 c00 = *(const bf16x8*)&wb[lane * 8];
                bf16x8 c01 = *(const bf16x8*)&wb[512 + lane * 8];
                bf16x8 c10 = *(const bf16x8*)&wb[1024 + lane * 8];
                bf16x8 c11 = *(const bf16x8*)&wb[1536 + lane * 8];
                float bias0 = s_bias[fbase];
                float bias1 = s_bias[fbase + 16];
                f32x4 acc0 = {0.f, 0.f, 0.f, 0.f}, acc1 = {0.f, 0.f, 0.f, 0.f};
                acc0 = __builtin_amdgcn_mfma_f32_16x16x32_bf16(a0, c00, acc0, 0, 0, 0);
                acc0 = __builtin_amdgcn_mfma_f32_16x16x32_bf16(a1, c01, acc0, 0, 0, 0);
                acc1 = __builtin_amdgcn_mfma_f32_16x16x32_bf16(a0, c10, acc1, 0, 0, 0);
                acc1 = __builtin_amdgcn_mfma_f32_16x16x32_bf16(a1, c11, acc1, 0, 0, 0);
                // relu(a+b) > t  <=>  a > t-b  (t > 0 always)
                float u0 = t0 - bias0, u1 = t1 - bias0, u2 = t2 - bias0, u3 = t3 - bias0;
                float v0 = t0 - bias1, v1 = t1 - bias1, v2 = t2 - bias1, v3 = t3 - bias1;
                PUSHI(acc0, fbase, u0, u1, u2, u3)
                PUSHI(acc1, fbase + 16, v0, v1, v2, v3)
            }
            __syncthreads();
            if (tid == 0) s_anybad = 0;
            __syncthreads();
            if (tid < ROWS) {
                int c = s_cnt[tid];
                bool lo = (c < KSEL), hi = (c > CAP);
                bool bad = (lo || hi) && (attempt < 7);
                s_act[tid] = bad ? 1 : 0;
                if (bad) { s_scale[tid] *= (lo ? 0.85f : 1.15f); s_cnt[tid] = 0; atomicAdd(&s_anybad, 1); }
            }
            __syncthreads();
            if (s_anybad == 0) break;
        }

        // ==== coalesced exact rescue (bit-exact R9) + radix select + decode ====
#pragma unroll 1
        for (int q2 = 0; q2 < 2; ++q2) {
            const int r = wu * 2 + q2;
            int n = s_cnt[r]; if (n > CAP) n = CAP;
            const int kq = lane & 15;
            const int cg = lane >> 4;
            const float4 xv = ((const float4*)s_xf32)[r * 16 + kq];
#pragma unroll 4
            for (int s = 0; s < n; s += 4) {
                const int sc = s + cg;
                unsigned j = (sc < n) ? s_buf[r * CAP + sc].y : 0u;
                float4 wv = ((const float4*)We)[(size_t)j * 16 + kq];
                float d = fmaf(wv.x, xv.x, fmaf(wv.y, xv.y, fmaf(wv.z, xv.z, wv.w * xv.w)));
                d += __shfl_xor(d, 1, 64); d += __shfl_xor(d, 2, 64);
                d += __shfl_xor(d, 4, 64); d += __shfl_xor(d, 8, 64);
                if (kq == 0 && sc < n)
                    s_buf[r * CAP + sc].x = __float_as_uint(fmaxf(d + s_bias[j], 0.f));
            }
            // keys: (exact valbits << 32) | ~idx  (distinct; low index wins ties)
            u64 k0 = 0ull, k1 = 0ull;
            if (lane < n)      { uint2 pp = s_buf[r * CAP + lane];      k0 = ((u64)pp.x << 32) | (unsigned)(~pp.y); }
            if (lane + 64 < n) { uint2 pp = s_buf[r * CAP + lane + 64]; k1 = ((u64)pp.x << 32) | (unsigned)(~pp.y); }
            // radix select: T = KSEL-th largest key
            u64 T = 0ull;
#pragma unroll 1
            for (int b = 62; b >= 32; --b) {
                u64 cand = T | (1ull << b);
                int c = __popcll(__ballot(k0 >= cand)) + __popcll(__ballot(k1 >= cand));
                if (c >= KSEL) T = cand;
            }
            T |= 0xFFFFF000ull;      // idx < 4096 -> ~idx bits 31..12 always set
#pragma unroll 1
            for (int b = 11; b >= 0; --b) {
                u64 cand = T | (1ull << b);
                int c = __popcll(__ballot(k0 >= cand)) + __popcll(__ballot(k1 >= cand));
                if (c >= KSEL) T = cand;
            }
            // compact exactly-KSEL selected keys into slots [0, KSEL)
            bool f0 = (k0 >= T), f1 = (k1 >= T);
            u64 m0 = __ballot(f0), m1 = __ballot(f1);
            u64 below = (1ull << lane) - 1ull;
            int r0 = __popcll(m0 & below);
            int r1 = __popcll(m0) + __popcll(m1 & below);
            if (f0) s_buf[r * CAP + r0] = make_uint2((unsigned)(k0 >> 32), ~(unsigned)k0);
            if (f1) s_buf[r * CAP + r1] = make_uint2((unsigned)(k1 >> 32), ~(unsigned)k1);
            // decode: rec = bdv + sum z_t * Wd[idx_t] (coalesced row reads)
            float rec = bdv[lane];
#pragma unroll 2
            for (int t = 0; t < KSEL; t += 4) {
                uint2 e0 = s_buf[r * CAP + t + 0];
                uint2 e1 = s_buf[r * CAP + t + 1];
                uint2 e2 = s_buf[r * CAP + t + 2];
                uint2 e3 = s_buf[r * CAP + t + 3];
                float w0 = Wd[(size_t)e0.y * D64 + lane];
                float w1 = Wd[(size_t)e1.y * D64 + lane];
                float w2 = Wd[(size_t)e2.y * D64 + lane];
                float w3 = Wd[(size_t)e3.y * D64 + lane];
                rec = fmaf(__uint_as_float(e0.x), w0, rec);
                rec = fmaf(__uint_as_float(e1.x), w1, rec);
                rec = fmaf(__uint_as_float(e2.x), w2, rec);
                rec = fmaf(__uint_as_float(e3.x), w3, rec);
            }
            if (level == 0) {
                float e = wave_sum_f32(rec * rec);
                if (lane == 0) s_sig[r] = 0.2625f * sqrtf(e); // 2.1*sigma for level 1
                s_xf32[r * D64 + lane] = rec;                 // exact recon0
                s_ah[r * D64 + lane] = f2bf(rec);             // bf16 A for level 1
            } else {
                float rec0 = s_xf32[r * D64 + lane];
                out[(size_t)(rowbase + r) * D64 + lane] =
                    (1.0f / 1.5f) * rec0 + (0.5f / 1.5f) * rec;
            }
        }
        if (level == 0) {
            __syncthreads();
            if (tid < ROWS) { s_cnt[tid] = 0; s_scale[tid] = 1.0f; s_act[tid] = 1; }
        }
    }
}

extern "C" void kernel_launch(void* const* d_in, const int* in_sizes, int n_in,
                              void* d_out, int out_size, void* d_ws, size_t ws_size,
                              hipStream_t stream) {
    (void)n_in; (void)out_size; (void)ws_size;
    const float* x   = (const float*)d_in[0];
    const float* W1  = (const float*)d_in[1];
    const float* b1  = (const float*)d_in[2];
    const float* Wd1 = (const float*)d_in[3];
    const float* bd1 = (const float*)d_in[4];
    const float* W2  = (const float*)d_in[5];
    const float* b2  = (const float*)d_in[6];
    const float* Wd2 = (const float*)d_in[7];
    const float* bd2 = (const float*)d_in[8];
    unsigned short* wh = (unsigned short*)d_ws;   // 768 KB bf16 packed weights

    // (4096+2048) rows x 8 chunks = 49152 threads
    prep_w<<<(HID1 + HID2) * 8 / 256, 256, 0, stream>>>(W1, W2, wh);

    const int batch = in_sizes[0] / D64;     // 16384
    const int grid  = batch / ROWS;          // 1024 blocks

    sae_hier_mfma<<<grid, 512, 0, stream>>>(x, W1, b1, Wd1, bd1, W2, b2, Wd2, bd2,
                                            wh, (float*)d_out);
}

// Round 28
// 106.173 us; speedup vs baseline: 1.2515x; 1.2515x over previous
//
#include <hip/hip_runtime.h>
#include <math.h>

// SAE hierarchical, R28 = R24 verbatim (revert after R26/R27 ballot-push
// faults). Best passing configuration: 106.5us, absmax 0.0625.
// Embodies all validated session wins: MFMA bf16 approx + exact fp32 rescue
// (R7), fragment-packed weights (R16), no cross-backedge prefetch (R20),
// 2.1-sigma index-only push (R23), LDS-staged biases (R24), waves_per_eu(8,8)
// (R17). Ballot-push (R26/27) abandoned: two unlocalized memory faults.

#define D64   64
#define ROWS  16
#define CAP   128
#define FTILE 256
#define HID1  4096
#define HID2  2048
#define K1    32
#define K2    16

typedef __attribute__((ext_vector_type(8))) short bf16x8;
typedef __attribute__((ext_vector_type(4))) float f32x4;
typedef unsigned long long u64;

__device__ __forceinline__ unsigned short f2bf(float f) {
    unsigned u = __float_as_uint(f);
    return (unsigned short)((u + 0x7FFFu + ((u >> 16) & 1u)) >> 16);
}

__device__ __forceinline__ float wave_sum_f32(float v) {
#pragma unroll
    for (int off = 32; off > 0; off >>= 1) v += __shfl_xor(v, off, 64);
    return v;
}

// prep: W1|W2 fp32 -> bf16, FRAGMENT-PACKED layout (R16/R20 mapping).
__global__ __launch_bounds__(256) void prep_w(const float* __restrict__ W1,
                                              const float* __restrict__ W2,
                                              unsigned short* __restrict__ wh) {
    const int t = blockIdx.x * 256 + threadIdx.x;    // 49152 threads, 8 floats each
    const int fg = t >> 3;                           // global feature 0..6143
    const int k8 = t & 7;                            // 8-halfword chunk
    const int lvl = (fg >= HID1);
    const int f = lvl ? fg - HID1 : fg;
    const float* src = lvl ? (W2 + (size_t)f * D64) : (W1 + (size_t)f * D64);
    const int p = f >> 8, rem = f & 255;
    const int wu = rem >> 5, half = (rem >> 4) & 1, l15 = rem & 15;
    const int frag = half * 2 + (k8 >= 4 ? 1 : 0);
    const int g = k8 & 3;
    float4 a = ((const float4*)src)[k8 * 2];
    float4 b = ((const float4*)src)[k8 * 2 + 1];
    u64 pk0 = (u64)f2bf(a.x) | ((u64)f2bf(a.y) << 16)
            | ((u64)f2bf(a.z) << 32) | ((u64)f2bf(a.w) << 48);
    u64 pk1 = (u64)f2bf(b.x) | ((u64)f2bf(b.y) << 16)
            | ((u64)f2bf(b.z) << 32) | ((u64)f2bf(b.w) << 48);
    const size_t dst = (size_t)(lvl ? HID1 * D64 : 0)
                     + (size_t)(((p * 8 + wu) * 4 + frag) * 512 + (g * 16 + l15) * 8);
    *(u64*)&wh[dst]     = pk0;
    *(u64*)&wh[dst + 4] = pk1;
}

__global__ __launch_bounds__(512)
__attribute__((amdgpu_waves_per_eu(8, 8)))
void sae_hier_mfma(
    const float* __restrict__ x,
    const float* __restrict__ W1,  const float* __restrict__ b1,
    const float* __restrict__ Wd1, const float* __restrict__ bd1,
    const float* __restrict__ W2,  const float* __restrict__ b2,
    const float* __restrict__ Wd2, const float* __restrict__ bd2,
    const unsigned short* __restrict__ wh,
    float* __restrict__ out)
{
    __shared__ uint2 s_buf[ROWS * CAP];                       // 16 KB candidates
    __shared__ __align__(16) float s_xf32[ROWS * D64];        // 4 KB exact input
    __shared__ __align__(16) unsigned short s_ah[ROWS * D64]; // 2 KB bf16 A (linear)
    __shared__ __align__(16) float s_bias[HID1];              // 16 KB staged biases
    __shared__ float s_sig[ROWS];
    __shared__ float s_thr[ROWS];
    __shared__ float s_scale[ROWS];
    __shared__ int   s_cnt[ROWS];
    __shared__ int   s_act[ROWS];
    __shared__ int   s_anybad;

    const int tid  = threadIdx.x;
    const int lane = tid & 63;
    const int wu   = __builtin_amdgcn_readfirstlane(tid >> 6);  // 8 waves
    const int rowbase = blockIdx.x * ROWS;
    const int g   = lane >> 4;
    const int l15 = lane & 15;

    if (tid < ROWS) { s_cnt[tid] = 0; s_scale[tid] = 1.0f; s_act[tid] = 1; }

    // ---- stage (x - b_dec): fp32 exact + bf16 linear + threshold base ----
    if (tid < 256) {
        const int r = tid >> 4, q = tid & 15;                 // 16 rows x 16 quads
        float4 a = ((const float4*)x)[(size_t)(rowbase + r) * 16 + q];
        float4 b = ((const float4*)bd1)[q];
        float4 v = make_float4(a.x - b.x, a.y - b.y, a.z - b.z, a.w - b.w);
        ((float4*)s_xf32)[r * 16 + q] = v;
        u64 pk = (u64)f2bf(v.x) | ((u64)f2bf(v.y) << 16)
               | ((u64)f2bf(v.z) << 32) | ((u64)f2bf(v.w) << 48);
        *(u64*)&s_ah[(r * 16 + q) * 4] = pk;
        float ss = fmaf(v.x, v.x, fmaf(v.y, v.y, fmaf(v.z, v.z, v.w * v.w)));
        ss += __shfl_xor(ss, 1, 64); ss += __shfl_xor(ss, 2, 64);
        ss += __shfl_xor(ss, 4, 64); ss += __shfl_xor(ss, 8, 64);
        if (q == 0) s_sig[r] = 0.2625f * sqrtf(ss);           // 2.1*sigma
    }

// index-only push: rescue overwrites .x with the exact value, so only .y matters.
#define PUSHI(ACC, COLG, U0, U1, U2, U3) { \
    if (ACC[0] > U0) { int s = atomicAdd(&s_cnt[g*4+0], 1); if (s < CAP) s_buf[(g*4+0)*CAP+s].y = (unsigned)(COLG); } \
    if (ACC[1] > U1) { int s = atomicAdd(&s_cnt[g*4+1], 1); if (s < CAP) s_buf[(g*4+1)*CAP+s].y = (unsigned)(COLG); } \
    if (ACC[2] > U2) { int s = atomicAdd(&s_cnt[g*4+2], 1); if (s < CAP) s_buf[(g*4+2)*CAP+s].y = (unsigned)(COLG); } \
    if (ACC[3] > U3) { int s = atomicAdd(&s_cnt[g*4+3], 1); if (s < CAP) s_buf[(g*4+3)*CAP+s].y = (unsigned)(COLG); } }

#pragma unroll 1
    for (int level = 0; level < 2; ++level) {
        const float* We  = level ? W2  : W1;
        const float* be  = level ? b2  : b1;
        const float* Wd  = level ? Wd2 : Wd1;
        const float* bdv = level ? bd2 : bd1;
        const unsigned short* whL = wh + (level ? (size_t)HID1 * D64 : 0);
        const int KSEL   = level ? K2 : K1;
        const int NPASS  = (level ? HID2 : HID1) / FTILE;
        const int NB     = level ? HID2 : HID1;

        // stage biases into LDS (once per level; coalesced float4)
        for (int i = tid; i < NB / 4; i += 512)
            ((float4*)s_bias)[i] = ((const float4*)be)[i];
        __syncthreads();

        // ======== approx GEMM (packed frags, LDS biases, index-only push) ========
#pragma unroll 1
        for (int attempt = 0; attempt < 8; ++attempt) {
            if (tid < ROWS) s_thr[tid] = s_act[tid] ? s_sig[tid] * s_scale[tid] : 3.4e38f;
            __syncthreads();
            bf16x8 a0 = *(const bf16x8*)&s_ah[l15 * D64 + 8 * g];
            bf16x8 a1 = *(const bf16x8*)&s_ah[l15 * D64 + 32 + 8 * g];
            const float t0 = s_thr[g * 4 + 0], t1 = s_thr[g * 4 + 1];
            const float t2 = s_thr[g * 4 + 2], t3 = s_thr[g * 4 + 3];

#pragma unroll 1
            for (int p = 0; p < NPASS; ++p) {
                const unsigned short* wb = whL + (size_t)(p * 8 + wu) * 2048;
                const int fbase = p * FTILE + wu * 32 + l15;
                // batch: 4 packed fragment loads (VMEM) + 2 bias ds_reads
                bf16x8 c00 = *(const bf16x8*)&wb[lane * 8];
                bf16x8 c01 = *(const bf16x8*)&wb[512 + lane * 8];
                bf16x8 c10 = *(const bf16x8*)&wb[1024 + lane * 8];
                bf16x8 c11 = *(const bf16x8*)&wb[1536 + lane * 8];
                float bias0 = s_bias[fbase];
                float bias1 = s_bias[fbase + 16];
                f32x4 acc0 = {0.f, 0.f, 0.f, 0.f}, acc1 = {0.f, 0.f, 0.f, 0.f};
                acc0 = __builtin_amdgcn_mfma_f32_16x16x32_bf16(a0, c00, acc0, 0, 0, 0);
                acc0 = __builtin_amdgcn_mfma_f32_16x16x32_bf16(a1, c01, acc0, 0, 0, 0);
                acc1 = __builtin_amdgcn_mfma_f32_16x16x32_bf16(a0, c10, acc1, 0, 0, 0);
                acc1 = __builtin_amdgcn_mfma_f32_16x16x32_bf16(a1, c11, acc1, 0, 0, 0);
                // relu(a+b) > t  <=>  a > t-b  (t > 0 always)
                float u0 = t0 - bias0, u1 = t1 - bias0, u2 = t2 - bias0, u3 = t3 - bias0;
                float v0 = t0 - bias1, v1 = t1 - bias1, v2 = t2 - bias1, v3 = t3 - bias1;
                PUSHI(acc0, fbase, u0, u1, u2, u3)
                PUSHI(acc1, fbase + 16, v0, v1, v2, v3)
            }
            __syncthreads();
            if (tid == 0) s_anybad = 0;
            __syncthreads();
            if (tid < ROWS) {
                int c = s_cnt[tid];
                bool lo = (c < KSEL), hi = (c > CAP);
                bool bad = (lo || hi) && (attempt < 7);
                s_act[tid] = bad ? 1 : 0;
                if (bad) { s_scale[tid] *= (lo ? 0.85f : 1.15f); s_cnt[tid] = 0; atomicAdd(&s_anybad, 1); }
            }
            __syncthreads();
            if (s_anybad == 0) break;
        }

        // ==== coalesced exact rescue (bit-exact R9) + radix select + decode ====
#pragma unroll 1
        for (int q2 = 0; q2 < 2; ++q2) {
            const int r = wu * 2 + q2;
            int n = s_cnt[r]; if (n > CAP) n = CAP;
            const int kq = lane & 15;
            const int cg = lane >> 4;
            const float4 xv = ((const float4*)s_xf32)[r * 16 + kq];
#pragma unroll 4
            for (int s = 0; s < n; s += 4) {
                const int sc = s + cg;
                unsigned j = (sc < n) ? s_buf[r * CAP + sc].y : 0u;
                float4 wv = ((const float4*)We)[(size_t)j * 16 + kq];
                float d = fmaf(wv.x, xv.x, fmaf(wv.y, xv.y, fmaf(wv.z, xv.z, wv.w * xv.w)));
                d += __shfl_xor(d, 1, 64); d += __shfl_xor(d, 2, 64);
                d += __shfl_xor(d, 4, 64); d += __shfl_xor(d, 8, 64);
                if (kq == 0 && sc < n)
                    s_buf[r * CAP + sc].x = __float_as_uint(fmaxf(d + s_bias[j], 0.f));
            }
            // keys: (exact valbits << 32) | ~idx  (distinct; low index wins ties)
            u64 k0 = 0ull, k1 = 0ull;
            if (lane < n)      { uint2 pp = s_buf[r * CAP + lane];      k0 = ((u64)pp.x << 32) | (unsigned)(~pp.y); }
            if (lane + 64 < n) { uint2 pp = s_buf[r * CAP + lane + 64]; k1 = ((u64)pp.x << 32) | (unsigned)(~pp.y); }
            // radix select: T = KSEL-th largest key
            u64 T = 0ull;
#pragma unroll 1
            for (int b = 62; b >= 32; --b) {
                u64 cand = T | (1ull << b);
                int c = __popcll(__ballot(k0 >= cand)) + __popcll(__ballot(k1 >= cand));
                if (c >= KSEL) T = cand;
            }
            T |= 0xFFFFF000ull;      // idx < 4096 -> ~idx bits 31..12 always set
#pragma unroll 1
            for (int b = 11; b >= 0; --b) {
                u64 cand = T | (1ull << b);
                int c = __popcll(__ballot(k0 >= cand)) + __popcll(__ballot(k1 >= cand));
                if (c >= KSEL) T = cand;
            }
            // compact exactly-KSEL selected keys into slots [0, KSEL)
            bool f0 = (k0 >= T), f1 = (k1 >= T);
            u64 m0 = __ballot(f0), m1 = __ballot(f1);
            u64 below = (1ull << lane) - 1ull;
            int r0 = __popcll(m0 & below);
            int r1 = __popcll(m0) + __popcll(m1 & below);
            if (f0) s_buf[r * CAP + r0] = make_uint2((unsigned)(k0 >> 32), ~(unsigned)k0);
            if (f1) s_buf[r * CAP + r1] = make_uint2((unsigned)(k1 >> 32), ~(unsigned)k1);
            // decode: rec = bdv + sum z_t * Wd[idx_t] (coalesced row reads)
            float rec = bdv[lane];
#pragma unroll 2
            for (int t = 0; t < KSEL; t += 4) {
                uint2 e0 = s_buf[r * CAP + t + 0];
                uint2 e1 = s_buf[r * CAP + t + 1];
                uint2 e2 = s_buf[r * CAP + t + 2];
                uint2 e3 = s_buf[r * CAP + t + 3];
                float w0 = Wd[(size_t)e0.y * D64 + lane];
                float w1 = Wd[(size_t)e1.y * D64 + lane];
                float w2 = Wd[(size_t)e2.y * D64 + lane];
                float w3 = Wd[(size_t)e3.y * D64 + lane];
                rec = fmaf(__uint_as_float(e0.x), w0, rec);
                rec = fmaf(__uint_as_float(e1.x), w1, rec);
                rec = fmaf(__uint_as_float(e2.x), w2, rec);
                rec = fmaf(__uint_as_float(e3.x), w3, rec);
            }
            if (level == 0) {
                float e = wave_sum_f32(rec * rec);
                if (lane == 0) s_sig[r] = 0.2625f * sqrtf(e); // 2.1*sigma for level 1
                s_xf32[r * D64 + lane] = rec;                 // exact recon0
                s_ah[r * D64 + lane] = f2bf(rec);             // bf16 A for level 1
            } else {
                float rec0 = s_xf32[r * D64 + lane];
                out[(size_t)(rowbase + r) * D64 + lane] =
                    (1.0f / 1.5f) * rec0 + (0.5f / 1.5f) * rec;
            }
        }
        if (level == 0) {
            __syncthreads();
            if (tid < ROWS) { s_cnt[tid] = 0; s_scale[tid] = 1.0f; s_act[tid] = 1; }
        }
    }
}

extern "C" void kernel_launch(void* const* d_in, const int* in_sizes, int n_in,
                              void* d_out, int out_size, void* d_ws, size_t ws_size,
                              hipStream_t stream) {
    (void)n_in; (void)out_size; (void)ws_size;
    const float* x   = (const float*)d_in[0];
    const float* W1  = (const float*)d_in[1];
    const float* b1  = (const float*)d_in[2];
    const float* Wd1 = (const float*)d_in[3];
    const float* bd1 = (const float*)d_in[4];
    const float* W2  = (const float*)d_in[5];
    const float* b2  = (const float*)d_in[6];
    const float* Wd2 = (const float*)d_in[7];
    const float* bd2 = (const float*)d_in[8];
    unsigned short* wh = (unsigned short*)d_ws;   // 768 KB bf16 packed weights

    // (4096+2048) rows x 8 chunks = 49152 threads
    prep_w<<<(HID1 + HID2) * 8 / 256, 256, 0, stream>>>(W1, W2, wh);

    const int batch = in_sizes[0] / D64;     // 16384
    const int grid  = batch / ROWS;          // 1024 blocks

    sae_hier_mfma<<<grid, 512, 0, stream>>>(x, W1, b1, Wd1, bd1, W2, b2, Wd2, bd2,
                                            wh, (float*)d_out);
}